// Round 1
// baseline (224.312 us; speedup 1.0000x reference)
//
#include <hip/hip_runtime.h>

// Problem constants (B=8, N=16384, E=64, F=64)
#define NPOS   (8 * 16384)      // 131072 positions (b,n)
#define E_DIM  64
#define F_DIM  64
#define PP     4                // positions per wave-iteration (phase-2 matrix-load amortization)
#define WAVES  4
#define THREADS (WAVES * 64)
#define GROUPS (NPOS / PP)      // 32768
#define BLOCKS 1024
#define NWAVES (BLOCKS * WAVES) // 4096
#define GROUPS_PER_WAVE (GROUPS / NWAVES) // 8 (exact)

// Repack A,Bw,C (each [F][E]) into e-major fused layout:
// Mt[e*192 + f*3 + {0,1,2}] = {A[f][e], Bw[f][e], C[f][e]}
// so phase-2 lane f reads 12 contiguous bytes per e (coalesced, 768B/wave).
__global__ void repack_mats(const float* __restrict__ A, const float* __restrict__ Bw,
                            const float* __restrict__ Cm, float* __restrict__ Mt) {
    int idx = blockIdx.x * 256 + threadIdx.x;
    if (idx >= E_DIM * F_DIM) return;
    int e = idx >> 6, f = idx & 63;
    Mt[e * 192 + f * 3 + 0] = A[f * E_DIM + e];
    Mt[e * 192 + f * 3 + 1] = Bw[f * E_DIM + e];
    Mt[e * 192 + f * 3 + 2] = Cm[f * E_DIM + e];
}

template <bool PACKED>
__global__ __launch_bounds__(THREADS)
void fused_kernel(const float* __restrict__ X, const float* __restrict__ J,
                  const float* __restrict__ Mt,
                  const float* __restrict__ A, const float* __restrict__ Bw,
                  const float* __restrict__ Cm, float* __restrict__ Y) {
    // Per-wave LDS slices; term layout: two float4 planes + one float plane.
    // plane0 = (a0,a1,a2,b0), plane1 = (b1,b2,c0,c1), plane2 = c2
    // Writes are lane-contiguous (stride 16B / 4B) -> conflict-free;
    // phase-2 reads are same-address broadcasts -> conflict-free.
    __shared__ float4 t01[WAVES][PP][2][E_DIM];  // 32 KiB
    __shared__ float  t2[WAVES][PP][E_DIM];      // 4 KiB
    const int w    = threadIdx.x >> 6;
    const int lane = threadIdx.x & 63;
    const int wave_id = blockIdx.x * WAVES + w;

    for (int g = 0; g < GROUPS_PER_WAVE; ++g) {
        const int group = wave_id * GROUPS_PER_WAVE + g;
        const int pbase = group * PP;

        // ---- Phase 1: lane = e. Compute R(J), v = R^T x, terms; stage to LDS.
        #pragma unroll
        for (int pl = 0; pl < PP; ++pl) {
            const int p = pbase + pl;
            const float* jp = J + (p * E_DIM + lane) * 3;
            const float* xp = X + (p * E_DIM + lane) * 3;
            float ja = jp[0], jb = jp[1], jg = jp[2];
            float sa, ca, sb, cb, sg, cg;
            __sincosf(ja, &sa, &ca);
            __sincosf(jb, &sb, &cb);
            __sincosf(jg, &sg, &cg);
            // R rows (r = row, c = col), ZYX euler per reference
            float casb = ca * sb, sasb = sa * sb;
            float r00 = ca * cb, r01 = casb * sg - sa * cg, r02 = casb * cg + sa * sg;
            float r10 = sa * cb, r11 = sasb * sg + ca * cg, r12 = sasb * cg - ca * sg;
            float r20 = -sb,     r21 = cb * sg,             r22 = cb * cg;
            float x0 = xp[0], x1 = xp[1], x2 = xp[2];
            // v_i = sum_k R[k][i] * x_k  (R^T x)
            float v0 = fmaf(r00, x0, fmaf(r10, x1, r20 * x2));
            float v1 = fmaf(r01, x0, fmaf(r11, x1, r21 * x2));
            float v2 = fmaf(r02, x0, fmaf(r12, x1, r22 * x2));
            // a[k] = R[k][0] v0 + R[k][1] v1 ; b[k] = R[k][1] v0 - R[k][0] v1 ; c[k] = R[k][2] v2
            float a0 = fmaf(r00, v0, r01 * v1);
            float a1 = fmaf(r10, v0, r11 * v1);
            float a2 = fmaf(r20, v0, r21 * v1);
            float b0 = fmaf(r01, v0, -r00 * v1);
            float b1 = fmaf(r11, v0, -r10 * v1);
            float b2 = fmaf(r21, v0, -r20 * v1);
            float c0 = r02 * v2, c1 = r12 * v2, c2 = r22 * v2;
            t01[w][pl][0][lane] = make_float4(a0, a1, a2, b0);
            t01[w][pl][1][lane] = make_float4(b1, b2, c0, c1);
            t2[w][pl][lane] = c2;
        }
        __syncthreads();

        // ---- Phase 2: lane = f. Y[p][f][i] = sum_e A[f][e]*a[e][i] + Bw[f][e]*b[e][i] + C[f][e]*c[e][i]
        float acc[PP][3];
        #pragma unroll
        for (int pl = 0; pl < PP; ++pl) {
            acc[pl][0] = 0.f; acc[pl][1] = 0.f; acc[pl][2] = 0.f;
        }
        #pragma unroll 4
        for (int e = 0; e < E_DIM; ++e) {
            float mA, mB, mC;
            if (PACKED) {
                const float* mp = Mt + e * 192 + lane * 3;
                mA = mp[0]; mB = mp[1]; mC = mp[2];
            } else {
                mA = A[lane * E_DIM + e];
                mB = Bw[lane * E_DIM + e];
                mC = Cm[lane * E_DIM + e];
            }
            #pragma unroll
            for (int pl = 0; pl < PP; ++pl) {
                float4 p0 = t01[w][pl][0][e];   // broadcast
                float4 p1 = t01[w][pl][1][e];   // broadcast
                float  cz = t2[w][pl][e];       // broadcast
                acc[pl][0] = fmaf(mA, p0.x, fmaf(mB, p0.w, fmaf(mC, p1.z, acc[pl][0])));
                acc[pl][1] = fmaf(mA, p0.y, fmaf(mB, p1.x, fmaf(mC, p1.w, acc[pl][1])));
                acc[pl][2] = fmaf(mA, p0.z, fmaf(mB, p1.y, fmaf(mC, cz,   acc[pl][2])));
            }
        }

        // ---- Store Y[p][f][0..2]
        #pragma unroll
        for (int pl = 0; pl < PP; ++pl) {
            const int p = pbase + pl;
            float* yp = Y + (p * F_DIM + lane) * 3;
            yp[0] = acc[pl][0];
            yp[1] = acc[pl][1];
            yp[2] = acc[pl][2];
        }
        __syncthreads();  // protect LDS before next group's phase 1
    }
}

extern "C" void kernel_launch(void* const* d_in, const int* in_sizes, int n_in,
                              void* d_out, int out_size, void* d_ws, size_t ws_size,
                              hipStream_t stream) {
    const float* X  = (const float*)d_in[0];
    const float* J  = (const float*)d_in[1];
    const float* A  = (const float*)d_in[2];
    const float* Bw = (const float*)d_in[3];
    const float* Cm = (const float*)d_in[4];
    float* Y = (float*)d_out;

    if (ws_size >= (size_t)(E_DIM * 192 * sizeof(float))) {
        float* Mt = (float*)d_ws;
        repack_mats<<<16, 256, 0, stream>>>(A, Bw, Cm, Mt);
        fused_kernel<true><<<BLOCKS, THREADS, 0, stream>>>(X, J, Mt, A, Bw, Cm, Y);
    } else {
        fused_kernel<false><<<BLOCKS, THREADS, 0, stream>>>(X, J, nullptr, A, Bw, Cm, Y);
    }
}

// Round 2
// 90.753 us; speedup vs baseline: 2.4717x; 2.4717x over previous
//
#include <hip/hip_runtime.h>

// B=8, N=16384, E=64, F=64. Positions = B*N = 131072.
// Formulation: Y[f, (p,i)] = sum_{kappa=0..191} Mcat[f][kappa] * T[p][kappa][i]
//   Mcat = [A | Bw | C] along kappa; T = [a_term; b_term; c_term].
// MFMA GEMM: M=64 (f), K=192, N=3*positions. mfma_f32_16x16x32_f16 tiles.

#define NPOS   131072
#define PB     32            // positions per block-iteration
#define NC     (PB * 3)      // 96 N-columns per block-iteration
#define ITERS  4
#define BLOCKS 1024          // 1024 * 4 * 32 = 131072 positions
#define THREADS 256          // 4 waves: wave w owns f-tile [16w, 16w+16)

typedef _Float16 half8 __attribute__((ext_vector_type(8)));
typedef float floatx4 __attribute__((ext_vector_type(4)));

__global__ __launch_bounds__(THREADS)
void fused_mfma(const float* __restrict__ X, const float* __restrict__ J,
                const float* __restrict__ A, const float* __restrict__ Bw,
                const float* __restrict__ Cm, float* __restrict__ Y) {
    // Fragment-ordered term buffer: T[ks][n][kg][j] <-> kappa = ks*32 + kg*8 + j.
    // Phase-2 read: lane reads 16B at [ks][nt*16+(l&15)][l>>4][0] ->
    // byte offsets (l&15)*64 + (l>>4)*16: exactly 8 dwords/bank (b128 ideal).
    __shared__ _Float16 Tl[6][NC][4][8];   // 36864 B -> 4 blocks/CU

    const int lane = threadIdx.x & 63;
    const int w    = threadIdx.x >> 6;

    // ---- Load Mcat fragments once; keep in registers for the whole kernel.
    // A-frag layout (16x32 tile, f-tile = w): lane holds
    // Mcat[f = 16w + (l&15)][k = ks*32 + (l>>4)*8 + j], j=0..7.
    const int fa  = w * 16 + (lane & 15);
    const int kgA = lane >> 4;
    half8 afrag[6];
    #pragma unroll
    for (int ks = 0; ks < 6; ++ks) {
        const float* mat = (ks < 2) ? A : (ks < 4 ? Bw : Cm);
        const float* src = mat + fa * 64 + (ks & 1) * 32 + kgA * 8;
        float4 lo = *(const float4*)src;
        float4 hi = *(const float4*)(src + 4);
        half8 h;
        h[0] = (_Float16)lo.x; h[1] = (_Float16)lo.y;
        h[2] = (_Float16)lo.z; h[3] = (_Float16)lo.w;
        h[4] = (_Float16)hi.x; h[5] = (_Float16)hi.y;
        h[6] = (_Float16)hi.z; h[7] = (_Float16)hi.w;
        afrag[ks] = h;
    }

    // Phase-1 write coordinates for this lane (e = lane):
    // kappa = t*64 + e -> ks = 2t + (e>>5), kg = (e&31)>>3, j = e&7.
    const int ks0 = lane >> 5;
    const int kgW = (lane & 31) >> 3;
    const int jW  = lane & 7;

    for (int it = 0; it < ITERS; ++it) {
        const int pbase = (blockIdx.x * ITERS + it) * PB;

        // ---- Phase 1: lane = e. 8 positions per wave. Terms -> LDS (f16).
        #pragma unroll
        for (int q = 0; q < 8; ++q) {
            const int p_local = w * 8 + q;
            const int p = pbase + p_local;
            const float* jp = J + (size_t)(p * 64 + lane) * 3;
            const float* xp = X + (size_t)(p * 64 + lane) * 3;
            float ja = jp[0], jb = jp[1], jg = jp[2];
            float x0 = xp[0], x1 = xp[1], x2 = xp[2];
            float sa, ca, sb, cb, sg, cg;
            __sincosf(ja, &sa, &ca);
            __sincosf(jb, &sb, &cb);
            __sincosf(jg, &sg, &cg);
            float casb = ca * sb, sasb = sa * sb;
            float r00 = ca * cb, r01 = casb * sg - sa * cg, r02 = casb * cg + sa * sg;
            float r10 = sa * cb, r11 = sasb * sg + ca * cg, r12 = sasb * cg - ca * sg;
            float r20 = -sb,     r21 = cb * sg,             r22 = cb * cg;
            // v = R^T x
            float v0 = fmaf(r00, x0, fmaf(r10, x1, r20 * x2));
            float v1 = fmaf(r01, x0, fmaf(r11, x1, r21 * x2));
            float v2 = fmaf(r02, x0, fmaf(r12, x1, r22 * x2));
            // terms (component k of a/b/c per reference)
            float a0 = fmaf(r00, v0, r01 * v1);
            float a1 = fmaf(r10, v0, r11 * v1);
            float a2 = fmaf(r20, v0, r21 * v1);
            float b0 = fmaf(r01, v0, -r00 * v1);
            float b1 = fmaf(r11, v0, -r10 * v1);
            float b2 = fmaf(r21, v0, -r20 * v1);
            float c0 = r02 * v2, c1 = r12 * v2, c2 = r22 * v2;

            const int n0 = p_local * 3;
            Tl[0 + ks0][n0 + 0][kgW][jW] = (_Float16)a0;
            Tl[0 + ks0][n0 + 1][kgW][jW] = (_Float16)a1;
            Tl[0 + ks0][n0 + 2][kgW][jW] = (_Float16)a2;
            Tl[2 + ks0][n0 + 0][kgW][jW] = (_Float16)b0;
            Tl[2 + ks0][n0 + 1][kgW][jW] = (_Float16)b1;
            Tl[2 + ks0][n0 + 2][kgW][jW] = (_Float16)b2;
            Tl[4 + ks0][n0 + 0][kgW][jW] = (_Float16)c0;
            Tl[4 + ks0][n0 + 1][kgW][jW] = (_Float16)c1;
            Tl[4 + ks0][n0 + 2][kgW][jW] = (_Float16)c2;
        }
        __syncthreads();

        // ---- Phase 2: wave w computes f-tile w over all 6 N-tiles, K=192.
        #pragma unroll
        for (int nt = 0; nt < 6; ++nt) {
            floatx4 acc = {0.f, 0.f, 0.f, 0.f};
            #pragma unroll
            for (int ks = 0; ks < 6; ++ks) {
                half8 b = *(const half8*)&Tl[ks][nt * 16 + (lane & 15)][lane >> 4][0];
                acc = __builtin_amdgcn_mfma_f32_16x16x32_f16(afrag[ks], b, acc, 0, 0, 0);
            }
            // Store: col n -> (p_local, i); rows f = 16w + (l>>4)*4 + r.
            const int n = nt * 16 + (lane & 15);
            const int pl2 = (n * 171) >> 9;      // n / 3 for n < 96
            const int i2  = n - pl2 * 3;
            const int p2  = pbase + pl2;
            float* yp = Y + (size_t)p2 * 192 + i2;
            const int fbase = w * 16 + (lane >> 4) * 4;
            #pragma unroll
            for (int r = 0; r < 4; ++r)
                yp[(fbase + r) * 3] = acc[r];
        }
        __syncthreads();
    }
}

extern "C" void kernel_launch(void* const* d_in, const int* in_sizes, int n_in,
                              void* d_out, int out_size, void* d_ws, size_t ws_size,
                              hipStream_t stream) {
    const float* X  = (const float*)d_in[0];
    const float* J  = (const float*)d_in[1];
    const float* A  = (const float*)d_in[2];
    const float* Bw = (const float*)d_in[3];
    const float* Cm = (const float*)d_in[4];
    float* Y = (float*)d_out;
    fused_mfma<<<BLOCKS, THREADS, 0, stream>>>(X, J, A, Bw, Cm, Y);
}

// Round 3
// 65.599 us; speedup vs baseline: 3.4194x; 1.3835x over previous
//
#include <hip/hip_runtime.h>

// B=8, N=16384, E=64, F=64. Positions = B*N = 131072.
// Y[f, (p,i)] = sum_{k=0..191} Mcat[f][k] * T[p][k][i];  Mcat = [A|Bw|C].
// MFMA GEMM (16x16x32 f16) with software pipeline:
//   per iter: barrier -> prefetch J/X(t+1) to regs -> P2(t): MFMA+store
//             -> P1(t+1): trig/terms -> ping-pong LDS buffer.

#define NPOS   131072
#define PB     16            // positions per block-iteration
#define NC     (PB * 3)      // 48 N-columns per iteration
#define ITERS  8
#define BLOCKS 1024          // 1024 * 8 * 16 = 131072
#define THREADS 256          // 4 waves; wave w owns f-tile [16w,16w+16)
#define PPW    4             // positions per wave per iteration

typedef _Float16 half8 __attribute__((ext_vector_type(8)));
typedef float floatx4 __attribute__((ext_vector_type(4)));

__global__ __launch_bounds__(THREADS, 4)
void fused_mfma(const float* __restrict__ X, const float* __restrict__ J,
                const float* __restrict__ A, const float* __restrict__ Bw,
                const float* __restrict__ Cm, float* __restrict__ Y) {
    // Fragment-ordered term buffer, ping-pong: kappa = ks*32 + kg*8 + j.
    // P2 read at [ks][nt*16+(l&15)][l>>4][0] -> byte off (l&15)*64+(l>>4)*16
    // = 8 dwords/bank (b128 ideal, conflict-free).
    __shared__ _Float16 Tl[2][6][NC][4][8];   // 2 x 18432 B = 36864 B

    const int lane = threadIdx.x & 63;
    const int w    = threadIdx.x >> 6;

    // ---- Mcat fragments in registers for the whole kernel.
    // lane holds Mcat[f = 16w+(l&15)][k = ks*32 + (l>>4)*8 + j], j=0..7.
    const int fa  = w * 16 + (lane & 15);
    const int kgA = lane >> 4;
    half8 afrag[6];
    #pragma unroll
    for (int ks = 0; ks < 6; ++ks) {
        const float* mat = (ks < 2) ? A : (ks < 4 ? Bw : Cm);
        const float* src = mat + fa * 64 + (ks & 1) * 32 + kgA * 8;
        float4 lo = *(const float4*)src;
        float4 hi = *(const float4*)(src + 4);
        half8 h;
        h[0] = (_Float16)lo.x; h[1] = (_Float16)lo.y;
        h[2] = (_Float16)lo.z; h[3] = (_Float16)lo.w;
        h[4] = (_Float16)hi.x; h[5] = (_Float16)hi.y;
        h[6] = (_Float16)hi.z; h[7] = (_Float16)hi.w;
        afrag[ks] = h;
    }

    // Phase-1 write coords (e = lane): ks = 2t + (e>>5), kg = (e&31)>>3, j = e&7.
    const int ks0 = lane >> 5;
    const int kgW = (lane & 31) >> 3;
    const int jW  = lane & 7;

    float jr[PPW][3], xr[PPW][3];   // prefetch registers (static-indexed)

    auto LOAD = [&](int it) {
        #pragma unroll
        for (int q = 0; q < PPW; ++q) {
            const int p = (blockIdx.x * ITERS + it) * PB + w * PPW + q;
            const float* jp = J + (size_t)(p * 64 + lane) * 3;
            const float* xp = X + (size_t)(p * 64 + lane) * 3;
            jr[q][0] = jp[0]; jr[q][1] = jp[1]; jr[q][2] = jp[2];
            xr[q][0] = xp[0]; xr[q][1] = xp[1]; xr[q][2] = xp[2];
        }
    };

    auto P1 = [&](int buf) {
        #pragma unroll
        for (int q = 0; q < PPW; ++q) {
            const int p_local = w * PPW + q;
            float ja = jr[q][0], jb = jr[q][1], jg = jr[q][2];
            float x0 = xr[q][0], x1 = xr[q][1], x2 = xr[q][2];
            float sa, ca, sb, cb, sg, cg;
            __sincosf(ja, &sa, &ca);
            __sincosf(jb, &sb, &cb);
            __sincosf(jg, &sg, &cg);
            float casb = ca * sb, sasb = sa * sb;
            float r00 = ca * cb, r01 = casb * sg - sa * cg, r02 = casb * cg + sa * sg;
            float r10 = sa * cb, r11 = sasb * sg + ca * cg, r12 = sasb * cg - ca * sg;
            float r20 = -sb,     r21 = cb * sg,             r22 = cb * cg;
            float v0 = fmaf(r00, x0, fmaf(r10, x1, r20 * x2));
            float v1 = fmaf(r01, x0, fmaf(r11, x1, r21 * x2));
            float v2 = fmaf(r02, x0, fmaf(r12, x1, r22 * x2));
            float a0 = fmaf(r00, v0, r01 * v1);
            float a1 = fmaf(r10, v0, r11 * v1);
            float a2 = fmaf(r20, v0, r21 * v1);
            float b0 = fmaf(r01, v0, -r00 * v1);
            float b1 = fmaf(r11, v0, -r10 * v1);
            float b2 = fmaf(r21, v0, -r20 * v1);
            float c0 = r02 * v2, c1 = r12 * v2, c2 = r22 * v2;

            const int n0 = p_local * 3;
            Tl[buf][0 + ks0][n0 + 0][kgW][jW] = (_Float16)a0;
            Tl[buf][0 + ks0][n0 + 1][kgW][jW] = (_Float16)a1;
            Tl[buf][0 + ks0][n0 + 2][kgW][jW] = (_Float16)a2;
            Tl[buf][2 + ks0][n0 + 0][kgW][jW] = (_Float16)b0;
            Tl[buf][2 + ks0][n0 + 1][kgW][jW] = (_Float16)b1;
            Tl[buf][2 + ks0][n0 + 2][kgW][jW] = (_Float16)b2;
            Tl[buf][4 + ks0][n0 + 0][kgW][jW] = (_Float16)c0;
            Tl[buf][4 + ks0][n0 + 1][kgW][jW] = (_Float16)c1;
            Tl[buf][4 + ks0][n0 + 2][kgW][jW] = (_Float16)c2;
        }
    };

    auto P2 = [&](int it, int buf) {
        #pragma unroll
        for (int nt = 0; nt < 3; ++nt) {
            floatx4 acc = {0.f, 0.f, 0.f, 0.f};
            #pragma unroll
            for (int ks = 0; ks < 6; ++ks) {
                half8 b = *(const half8*)&Tl[buf][ks][nt * 16 + (lane & 15)][lane >> 4][0];
                acc = __builtin_amdgcn_mfma_f32_16x16x32_f16(afrag[ks], b, acc, 0, 0, 0);
            }
            const int n = nt * 16 + (lane & 15);
            const int pl2 = (n * 171) >> 9;      // n/3 for n < 96
            const int i2  = n - pl2 * 3;
            const int p2  = (blockIdx.x * ITERS + it) * PB + pl2;
            float* yp = Y + (size_t)p2 * 192 + i2;
            const int fbase = w * 16 + (lane >> 4) * 4;
            #pragma unroll
            for (int r = 0; r < 4; ++r)
                __builtin_nontemporal_store(acc[r], &yp[(fbase + r) * 3]);
        }
    };

    // ---- Software pipeline: one barrier per iteration.
    LOAD(0);
    P1(0);                        // -> buf 0
    for (int t = 0; t < ITERS; ++t) {
        __syncthreads();          // buf[t&1] visible; prev P2 done with buf[(t+1)&1]
        if (t + 1 < ITERS) LOAD(t + 1);   // issue prefetch; hidden under P2
        P2(t, t & 1);
        if (t + 1 < ITERS) P1((t + 1) & 1);
    }
}

extern "C" void kernel_launch(void* const* d_in, const int* in_sizes, int n_in,
                              void* d_out, int out_size, void* d_ws, size_t ws_size,
                              hipStream_t stream) {
    const float* X  = (const float*)d_in[0];
    const float* J  = (const float*)d_in[1];
    const float* A  = (const float*)d_in[2];
    const float* Bw = (const float*)d_in[3];
    const float* Cm = (const float*)d_in[4];
    float* Y = (float*)d_out;
    fused_mfma<<<BLOCKS, THREADS, 0, stream>>>(X, J, A, Bw, Cm, Y);
}